// Round 8
// baseline (153.540 us; speedup 1.0000x reference)
//
#include <hip/hip_runtime.h>

// ---------------------------------------------------------------------------
// HierarchicalAffinityLoss on MI355X, fp16-MFMA, round 19.
// loss = mean_r relu(maxDot_diff(r) - minDot_same(r) + 0.3), dots of
// row-normalized embeddings. Self-exclusion via bias rank.
// R18 post-mortem: REGRESSION 62->85.7us. (a) VGPR stayed 76 — compiler
// re-scheduled the hand-rolled 5-deep window away (source order is not
// binding; m131-m141 lesson confirmed first-hand). (b) grid 768->512 cut
// occupancy 20.9->13.9%: kernel is GRID-limited, not register-limited
// (~180 regs/wave supports 8 waves/SIMD; at 768 blocks only 3 blocks/CU
// existed). Fewer waves -> less latency cover -> slower.
// R19 = R17 verbatim, ONE change: grid 768 -> 2048 (8 blocks/CU = 32
// waves/CU). TLP does the latency hiding that manual ILP couldn't.
// Structure (R17, proven 62us): NO LDS, NO barriers; fragment-linear EhB
// (every A/B fragment load = one coalesced 1KB wave-load); bias rank
// K=288 (dot' = dot - 8*[same], self-dot -7 never wins); symmetric
// atomic fold into mnK/mxK (uint min/max on +10-shifted f32 bits);
// triangle tasks rb in [0,64) x ct in [2rb,128); bijective XCD swizzle;
// flush on EVERY rb-crossing (R15 fix).
// ---------------------------------------------------------------------------

typedef __attribute__((ext_vector_type(8))) _Float16 half8;  // MFMA A/B frag
typedef __attribute__((ext_vector_type(4))) float floatx4;   // MFMA C/D
typedef __attribute__((ext_vector_type(4))) unsigned short ushort4v;

constexpr int DIN = 256;  // input embedding dim
constexpr int NKS = 9;    // K blocks of 32: 8 data + 1 bias
// fragment-linear tile: [ks 0..8][nj 0..3][lane 0..63][8 halves]
constexpr int TILE_USH = NKS * 4 * 64 * 8;   // 18432 ushorts = 36KB per tile
#define MARGIN 0.3f
// packed family table {0,1,2,1,3,3}, 3 bits each
#define FAM_PACKED 111240

static __device__ __forceinline__ unsigned fkey(float x) {
  return __builtin_bit_cast(unsigned, x + 10.0f);  // touched values > 0
}

// K1: grid-stride waves; row r -> tile ct=r>>6, nj=(r>>4)&3, mrow=r&15.
// Lane holds elems e=lane*4..+3: ks=lane>>3, q=(lane>>1)&3, o=(lane&1)*4.
// EhB[((ct*9+ks)*4+nj)*512 + (q*16+mrow)*8 + o] = fp16(E/||E||) (e<256);
// ks=8 block: 4*onehot(fam) at e=256..259, zeros elsewhere.
__global__ __launch_bounds__(256) void prep_kernel(
    const float* __restrict__ E, const int* __restrict__ labels,
    unsigned short* __restrict__ EhB, unsigned* __restrict__ mnK,
    unsigned* __restrict__ mxK, float* __restrict__ sumAcc,
    int* __restrict__ cntAcc, int* __restrict__ doneCnt, int B) {
  if (blockIdx.x == 0 && threadIdx.x == 0) {
    sumAcc[0] = 0.0f; cntAcc[0] = 0; doneCnt[0] = 0;
  }
  int gid = blockIdx.x * 256 + threadIdx.x;
  if (gid < B) { mnK[gid] = 0xFFFFFFFFu; mxK[gid] = 0u; }
  int wave = blockIdx.x * 4 + (threadIdx.x >> 6);
  int lane = threadIdx.x & 63;
  int nw   = gridDim.x * 4;
  const int ksl = lane >> 3, ql = (lane >> 1) & 3, ol = (lane & 1) * 4;
  for (int row = wave; row < B; row += nw) {
    float4 v = *(const float4*)&E[(long)row * DIN + lane * 4];
    float s = v.x * v.x + v.y * v.y + v.z * v.z + v.w * v.w;
#pragma unroll
    for (int o = 1; o < 64; o <<= 1) s += __shfl_xor(s, o);
    float rn = 1.0f / sqrtf(s);
    ushort4v o4;
    o4.x = __builtin_bit_cast(unsigned short, (_Float16)(v.x * rn));
    o4.y = __builtin_bit_cast(unsigned short, (_Float16)(v.y * rn));
    o4.z = __builtin_bit_cast(unsigned short, (_Float16)(v.z * rn));
    o4.w = __builtin_bit_cast(unsigned short, (_Float16)(v.w * rn));
    const int ct = row >> 6, nj = (row >> 4) & 3, mrow = row & 15;
    const long tbase = (long)ct * TILE_USH;
    *(ushort4v*)&EhB[tbase + ((long)(ksl * 4 + nj) * 64 + ql * 16 + mrow) * 8
                     + ol] = o4;
    if (lane < 8) {   // bias block ks=8: elems 256..287
      ushort4v z = {0, 0, 0, 0};
      if (lane == 0) {
        int lab = labels[row];
        int labc = lab < 0 ? 0 : (lab > 5 ? 5 : lab);
        int fm = (FAM_PACKED >> (3 * labc)) & 7;
        z.x = fm == 0 ? 0x4400 : 0;   // 4.0h
        z.y = fm == 1 ? 0x4400 : 0;
        z.z = fm == 2 ? 0x4400 : 0;
        z.w = fm == 3 ? 0x4400 : 0;
      }
      *(ushort4v*)&EhB[tbase + ((long)(8 * 4 + nj) * 64 + ql * 16 + mrow) * 8
                       + ol] = z;
    }
  }
}

// K2: block = 4 independent waves (no LDS, no barriers). Wave w owns rows
// rb*128+w*32 (A tile 2rb+(w>>1), frag cols (w&1)*2+mi) resident in regs.
// Tasks (rb, ct), ct in [2rb, nt); wave computes its 32x64 tile iff
// rt64 <= ct. All fragment loads are coalesced 1KB wave-loads from EhB.
__global__ __launch_bounds__(256, 2) void gram_kernel(
    const unsigned short* __restrict__ EhB, unsigned* __restrict__ mnK,
    unsigned* __restrict__ mxK, int nt, int nTasks) {
  const int w = threadIdx.x >> 6, l = threadIdx.x & 63;
  const int m = l & 15, q = l >> 4;

  // bijective XCD swizzle (gridDim % 8 == 0)
  const int nwg = gridDim.x;
  const int bid = (int)blockIdx.x;
  const int swz = (bid & 7) * (nwg >> 3) + (bid >> 3);

  const int t0 = (int)(((long)swz * nTasks) / nwg);
  const int t1 = (int)(((long)(swz + 1) * nTasks) / nwg);

  // decode t0 -> (rb, ct): C(rb) = rb*(nt-rb+1); C(rb+1) = (rb+1)*(nt-rb)
  int rb = 0;
  while ((rb + 1) * (nt - rb) <= t0) ++rb;
  int ct = 2 * rb + (t0 - rb * (nt - rb + 1));

  const unsigned short* baseL = EhB + l * 8;   // lane's fragment column

  half8 apan[NKS][2];   // 8 data K-blocks + bias (pre-scaled -0.5)
  auto loadA = [&](int rbv) {
    const long at = (long)(2 * rbv + (w >> 1)) * TILE_USH;
#pragma unroll
    for (int ks = 0; ks < NKS; ++ks)
#pragma unroll
      for (int mi = 0; mi < 2; ++mi)
        apan[ks][mi] = *(const half8*)
            &baseL[at + (long)(ks * 4 + (w & 1) * 2 + mi) * 512];
    apan[8][0] = apan[8][0] * (_Float16)-0.5f;   // 4*onehot -> -2*onehot
    apan[8][1] = apan[8][1] * (_Float16)-0.5f;
  };
  loadA(rb);

  float rAmn[8], rAmx[8];
  bool any = false;
#pragma unroll
  for (int i = 0; i < 8; ++i) { rAmn[i] = 100.0f; rAmx[i] = -100.0f; }

  auto flushRows = [&](int rbv) {
    if (!any) return;
#pragma unroll
    for (int o = 1; o < 16; o <<= 1)
#pragma unroll
      for (int i = 0; i < 8; ++i) {
        rAmn[i] = fminf(rAmn[i], __shfl_xor(rAmn[i], o));
        rAmx[i] = fmaxf(rAmx[i], __shfl_xor(rAmx[i], o));
      }
    if (m == 0) {
      const int r0 = rbv * 128 + w * 32 + q * 4;
#pragma unroll
      for (int mi = 0; mi < 2; ++mi)
#pragma unroll
        for (int r = 0; r < 4; ++r) {
          int row = r0 + mi * 16 + r;
          atomicMin(&mnK[row], fkey(rAmn[mi * 4 + r]));
          atomicMax(&mxK[row], fkey(rAmx[mi * 4 + r]));
        }
    }
  };

#pragma unroll 1
  for (int f = t0; f < t1; ++f) {
    const int rt64 = 2 * rb + (w >> 1);
    if (rt64 <= ct) {
      any = true;
      const unsigned short* bt = baseL + (long)ct * TILE_USH;
      floatx4 acc[2][4];
#pragma unroll
      for (int mi = 0; mi < 2; ++mi)
#pragma unroll
        for (int nj = 0; nj < 4; ++nj) acc[mi][nj] = (floatx4)0.0f;
#pragma unroll
      for (int ks = 0; ks < NKS; ++ks) {
        half8 b[4];
#pragma unroll
        for (int nj = 0; nj < 4; ++nj)
          b[nj] = *(const half8*)&bt[(long)(ks * 4 + nj) * 512];
#pragma unroll
        for (int mi = 0; mi < 2; ++mi)
#pragma unroll
          for (int nj = 0; nj < 4; ++nj)
            acc[mi][nj] = __builtin_amdgcn_mfma_f32_16x16x32_f16(
                apan[ks][mi], b[nj], acc[mi][nj], 0, 0, 0);
      }
      // ---- epilogue: biased extremes; C/D col = nj*16+m, row = mi*16+q*4+r
      float cMn[4], cMx[4];
#pragma unroll
      for (int nj = 0; nj < 4; ++nj) {
        float a0 = fminf(fminf(acc[0][nj][0], acc[0][nj][1]),
                         fminf(acc[0][nj][2], acc[0][nj][3]));
        float a1 = fminf(fminf(acc[1][nj][0], acc[1][nj][1]),
                         fminf(acc[1][nj][2], acc[1][nj][3]));
        float b0 = fmaxf(fmaxf(acc[0][nj][0], acc[0][nj][1]),
                         fmaxf(acc[0][nj][2], acc[0][nj][3]));
        float b1 = fmaxf(fmaxf(acc[1][nj][0], acc[1][nj][1]),
                         fmaxf(acc[1][nj][2], acc[1][nj][3]));
        cMn[nj] = fminf(a0, a1);
        cMx[nj] = fmaxf(b0, b1);
#pragma unroll
        for (int mi = 0; mi < 2; ++mi)
#pragma unroll
          for (int r = 0; r < 4; ++r) {
            rAmn[mi * 4 + r] = fminf(rAmn[mi * 4 + r], acc[mi][nj][r]);
            rAmx[mi * 4 + r] = fmaxf(rAmx[mi * 4 + r], acc[mi][nj][r]);
          }
      }
#pragma unroll
      for (int nj = 0; nj < 4; ++nj) {
        cMn[nj] = fminf(cMn[nj], __shfl_xor(cMn[nj], 16));
        cMn[nj] = fminf(cMn[nj], __shfl_xor(cMn[nj], 32));
        cMx[nj] = fmaxf(cMx[nj], __shfl_xor(cMx[nj], 16));
        cMx[nj] = fmaxf(cMx[nj], __shfl_xor(cMx[nj], 32));
      }
      if (q == 0) {
#pragma unroll
        for (int nj = 0; nj < 4; ++nj) {
          int col = ct * 64 + nj * 16 + m;
          atomicMin(&mnK[col], fkey(cMn[nj]));
          atomicMax(&mxK[col], fkey(cMx[nj]));
        }
      }
    }
    // advance; flush on EVERY rb-crossing (R15 fix)
    int nct = ct + 1, nrb = rb;
    if (nct == nt) { ++nrb; nct = 2 * nrb; }
    if (nrb != rb) {
      flushRows(rb);
#pragma unroll
      for (int i = 0; i < 8; ++i) { rAmn[i] = 100.0f; rAmx[i] = -100.0f; }
      any = false;
      if (f + 1 < t1) loadA(nrb);
    }
    rb = nrb; ct = nct;
  }
  flushRows(rb);   // no-op (any==false) if last task closed an rb
}

// K3: one thread per row. biasedMin = f(mnK)-10 (= minSame-8 iff < -4);
// biasedMax = f(mxK)-10 (= maxDiff iff > -4).
__global__ __launch_bounds__(256) void reduce_kernel(
    const unsigned* __restrict__ mnK, const unsigned* __restrict__ mxK,
    float* __restrict__ sumAcc, int* __restrict__ cntAcc,
    int* __restrict__ doneCnt, float* __restrict__ out, int B) {
  int gid = blockIdx.x * 256 + threadIdx.x;
  float loss = 0.0f;
  int cc = 0;
  if (gid < B) {
    float bmn = __builtin_bit_cast(float, mnK[gid]) - 10.0f;
    float bmx = __builtin_bit_cast(float, mxK[gid]) - 10.0f;
    if (bmn < -4.0f && bmx > -4.0f) {   // has same && has diff
      loss = fmaxf(bmx - (bmn + 8.0f) + MARGIN, 0.0f);
      cc = 1;
    }
  }
#pragma unroll
  for (int o = 1; o < 64; o <<= 1) {
    loss += __shfl_xor(loss, o);
    cc   += __shfl_xor(cc, o);
  }
  __shared__ float ls[4];
  __shared__ int   cs[4];
  if ((threadIdx.x & 63) == 0) {
    ls[threadIdx.x >> 6] = loss;
    cs[threadIdx.x >> 6] = cc;
  }
  __syncthreads();
  if (threadIdx.x == 0) {
    atomicAdd(sumAcc, ls[0] + ls[1] + ls[2] + ls[3]);
    atomicAdd(cntAcc, cs[0] + cs[1] + cs[2] + cs[3]);
    __threadfence();
    int old = atomicAdd(doneCnt, 1);
    if (old == (int)gridDim.x - 1) {
      float S = atomicAdd(sumAcc, 0.0f);   // coherent read
      int   C = atomicAdd(cntAcc, 0);
      out[0] = S / (float)(C > 0 ? C : 1);
    }
  }
}

extern "C" void kernel_launch(void* const* d_in, const int* in_sizes, int n_in,
                              void* d_out, int out_size, void* d_ws, size_t ws_size,
                              hipStream_t stream) {
  const float* E      = (const float*)d_in[0];
  const int*   labels = (const int*)d_in[1];
  float*       out    = (float*)d_out;
  const int B  = in_sizes[1];        // 8192
  const int nt = B / 64;             // 128 col tiles
  const int RB = B / 128;            // 64 row panels of 128 rows
  const int nTasks = RB * (nt - RB + 1);   // 64*65 = 4160

  // ws: EhB[nt*36KB] (4.72MB) | mnK[B] | mxK[B] | accums  (~4.79MB)
  unsigned short* EhB = (unsigned short*)d_ws;
  unsigned* mnK       = (unsigned*)(EhB + (size_t)nt * TILE_USH);
  unsigned* mxK       = mnK + B;
  float* sumAcc       = (float*)(mxK + B);
  int* cntAcc         = (int*)(sumAcc + 1);
  int* doneCnt        = cntAcc + 1;

  prep_kernel<<<dim3(256), 256, 0, stream>>>(E, labels, EhB, mnK, mxK,
                                             sumAcc, cntAcc, doneCnt, B);
  // grid 2048 = 8 blocks/CU resident (kernel is grid-limited, not
  // register-limited: ~180 regs/wave supports 8 waves/SIMD)
  gram_kernel<<<dim3(2048), 256, 0, stream>>>(EhB, mnK, mxK, nt, nTasks);
  reduce_kernel<<<dim3((B + 255) / 256), 256, 0, stream>>>(
      mnK, mxK, sumAcc, cntAcc, doneCnt, out, B);
}

// Round 9
// 102.991 us; speedup vs baseline: 1.4908x; 1.4908x over previous
//
#include <hip/hip_runtime.h>

// ---------------------------------------------------------------------------
// HierarchicalAffinityLoss on MI355X, fp16-MFMA, round 20.
// loss = mean_r relu(maxDot_diff(r) - minDot_same(r) + 0.3), dots of
// row-normalized embeddings. Self-exclusion via bias rank.
// R19 post-mortem: grid 2048 REGRESSED (62->89us), occupancy pinned ~20%
// regardless of grid -> residency-capped (~180 regs/wave ~ 2 blocks/CU).
// Root cause of the 62us: EhB (4.7MB) does NOT fit per-XCD L2 (4MB) ->
// B-frag reads are L3 hits (~600-900cyc); with a 1-batch register window
// and 2 waves/SIMD the latency is fully exposed (9 batches x ~800cyc).
// R20: LDS B-staging, T3 minimal 2-phase template (stage FIRST, compute,
// ONE vmcnt-drain+barrier per task). Fixes R11's two mistakes: R11
// prefetched AFTER compute (barrier drain ate full L3 latency) and staged
// from scattered row-major source. Here the 9 global_load_lds per thread
// are ~1.5k cyc old at the barrier (drain ~free) and stream contiguously
// from fragment-linear EhB. One staged tile serves all 4 waves: L3 B
// traffic drops 4x (600->150MB). A-panel stays in regs; atomic fold out.
// Floor: LDS-read 4160x144KB/256CU/85Bcyc ~ 11.5us.
//  * Bias rank K=288 (dot' = dot - 8*[same], self-dot -7 never wins).
//  * mnK/mxK[B] uint atomicMin/Max on +10-shifted f32 bits; row-side reg
//    accumulated per rb-segment, flushed at EVERY crossing (R15 fix).
//  * Triangle tasks rb in [0,64) x ct in [2rb,128); grid 512 = exactly
//    2 blocks/CU (LDS 72KB/block caps 2); bijective XCD swizzle.
// ---------------------------------------------------------------------------

typedef __attribute__((ext_vector_type(8))) _Float16 half8;  // MFMA A/B frag
typedef __attribute__((ext_vector_type(4))) float floatx4;   // MFMA C/D
typedef __attribute__((ext_vector_type(4))) unsigned short ushort4v;

constexpr int DIN = 256;  // input embedding dim
constexpr int NKS = 9;    // K blocks of 32: 8 data + 1 bias
// fragment-linear tile: [ks 0..8][nj 0..3][lane 0..63][8 halves]
constexpr int TILE_USH = NKS * 4 * 64 * 8;   // 18432 ushorts = 36KB per tile
#define MARGIN 0.3f
// packed family table {0,1,2,1,3,3}, 3 bits each
#define FAM_PACKED 111240

static __device__ __forceinline__ unsigned fkey(float x) {
  return __builtin_bit_cast(unsigned, x + 10.0f);  // touched values > 0
}

// async 16B global -> LDS (wave-uniform LDS base; HW adds lane*16)
static __device__ __forceinline__ void ld_g2l16(const unsigned short* g,
                                                unsigned short* lds) {
  __builtin_amdgcn_global_load_lds(
      (const __attribute__((address_space(1))) unsigned int*)(const void*)g,
      (__attribute__((address_space(3))) unsigned int*)(void*)lds, 16, 0, 0);
}

// K1: grid-stride waves; row r -> tile ct=r>>6, nj=(r>>4)&3, mrow=r&15.
// Lane holds elems e=lane*4..+3: ks=lane>>3, q=(lane>>1)&3, o=(lane&1)*4.
// EhB[((ct*9+ks)*4+nj)*512 + (q*16+mrow)*8 + o] = fp16(E/||E||) (e<256);
// ks=8 block: 4*onehot(fam) at e=256..259, zeros elsewhere.
__global__ __launch_bounds__(256) void prep_kernel(
    const float* __restrict__ E, const int* __restrict__ labels,
    unsigned short* __restrict__ EhB, unsigned* __restrict__ mnK,
    unsigned* __restrict__ mxK, float* __restrict__ sumAcc,
    int* __restrict__ cntAcc, int* __restrict__ doneCnt, int B) {
  if (blockIdx.x == 0 && threadIdx.x == 0) {
    sumAcc[0] = 0.0f; cntAcc[0] = 0; doneCnt[0] = 0;
  }
  int gid = blockIdx.x * 256 + threadIdx.x;
  if (gid < B) { mnK[gid] = 0xFFFFFFFFu; mxK[gid] = 0u; }
  int wave = blockIdx.x * 4 + (threadIdx.x >> 6);
  int lane = threadIdx.x & 63;
  int nw   = gridDim.x * 4;
  const int ksl = lane >> 3, ql = (lane >> 1) & 3, ol = (lane & 1) * 4;
  for (int row = wave; row < B; row += nw) {
    float4 v = *(const float4*)&E[(long)row * DIN + lane * 4];
    float s = v.x * v.x + v.y * v.y + v.z * v.z + v.w * v.w;
#pragma unroll
    for (int o = 1; o < 64; o <<= 1) s += __shfl_xor(s, o);
    float rn = 1.0f / sqrtf(s);
    ushort4v o4;
    o4.x = __builtin_bit_cast(unsigned short, (_Float16)(v.x * rn));
    o4.y = __builtin_bit_cast(unsigned short, (_Float16)(v.y * rn));
    o4.z = __builtin_bit_cast(unsigned short, (_Float16)(v.z * rn));
    o4.w = __builtin_bit_cast(unsigned short, (_Float16)(v.w * rn));
    const int ct = row >> 6, nj = (row >> 4) & 3, mrow = row & 15;
    const long tbase = (long)ct * TILE_USH;
    *(ushort4v*)&EhB[tbase + ((long)(ksl * 4 + nj) * 64 + ql * 16 + mrow) * 8
                     + ol] = o4;
    if (lane < 8) {   // bias block ks=8: elems 256..287
      ushort4v z = {0, 0, 0, 0};
      if (lane == 0) {
        int lab = labels[row];
        int labc = lab < 0 ? 0 : (lab > 5 ? 5 : lab);
        int fm = (FAM_PACKED >> (3 * labc)) & 7;
        z.x = fm == 0 ? 0x4400 : 0;   // 4.0h
        z.y = fm == 1 ? 0x4400 : 0;
        z.z = fm == 2 ? 0x4400 : 0;
        z.w = fm == 3 ? 0x4400 : 0;
      }
      *(ushort4v*)&EhB[tbase + ((long)(8 * 4 + nj) * 64 + ql * 16 + mrow) * 8
                       + ol] = z;
    }
  }
}

// K2: block = 4 waves. Wave w owns rows rb*128+w*32 (A tile 2rb+(w>>1),
// frag cols (w&1)*2+mi) in regs. Per task: B tile (36KB) staged once into
// LDS dbuf via global_load_lds (all 4 waves, 9 chunks/thread), 2-phase:
// barrier -> stage next (async) -> compute current from LDS -> repeat.
// Compiler emits the single vmcnt-drain before each s_barrier.
__global__ __launch_bounds__(256, 2) void gram_kernel(
    const unsigned short* __restrict__ EhB, unsigned* __restrict__ mnK,
    unsigned* __restrict__ mxK, int nt, int nTasks) {
  __shared__ unsigned short Bs[2][TILE_USH];   // 2 x 36KB

  const int w = threadIdx.x >> 6, l = threadIdx.x & 63;
  const int m = l & 15, q = l >> 4;

  // bijective XCD swizzle (gridDim % 8 == 0)
  const int nwg = gridDim.x;
  const int bid = (int)blockIdx.x;
  const int swz = (bid & 7) * (nwg >> 3) + (bid >> 3);

  const int t0 = (int)(((long)swz * nTasks) / nwg);
  const int t1 = (int)(((long)(swz + 1) * nTasks) / nwg);

  // decode t0 -> (rb, ct): C(rb) = rb*(nt-rb+1); C(rb+1) = (rb+1)*(nt-rb)
  int rb = 0;
  while ((rb + 1) * (nt - rb) <= t0) ++rb;
  int ct = 2 * rb + (t0 - rb * (nt - rb + 1));

  const unsigned short* baseL = EhB + l * 8;   // lane's fragment column (A)

  // stage B tile ctv into Bs[buf]: thread chunk j*256 + w*64 + l
  auto stage = [&](int buf, int ctv) {
    const unsigned short* src =
        EhB + (long)ctv * TILE_USH + (long)(w * 64 + l) * 8;
    unsigned short* dst = &Bs[buf][(w * 64) * 8];
#pragma unroll
    for (int j = 0; j < 9; ++j)
      ld_g2l16(src + j * 2048, dst + j * 2048);
  };

  half8 apan[NKS][2];   // 8 data K-blocks + bias (pre-scaled -0.5)
  auto loadA = [&](int rbv) {
    const long at = (long)(2 * rbv + (w >> 1)) * TILE_USH;
#pragma unroll
    for (int ks = 0; ks < NKS; ++ks)
#pragma unroll
      for (int mi = 0; mi < 2; ++mi)
        apan[ks][mi] = *(const half8*)
            &baseL[at + (long)(ks * 4 + (w & 1) * 2 + mi) * 512];
    apan[8][0] = apan[8][0] * (_Float16)-0.5f;   // 4*onehot -> -2*onehot
    apan[8][1] = apan[8][1] * (_Float16)-0.5f;
  };
  loadA(rb);

  float rAmn[8], rAmx[8];
  bool any = false;
#pragma unroll
  for (int i = 0; i < 8; ++i) { rAmn[i] = 100.0f; rAmx[i] = -100.0f; }

  auto flushRows = [&](int rbv) {
    if (!any) return;
#pragma unroll
    for (int o = 1; o < 16; o <<= 1)
#pragma unroll
      for (int i = 0; i < 8; ++i) {
        rAmn[i] = fminf(rAmn[i], __shfl_xor(rAmn[i], o));
        rAmx[i] = fmaxf(rAmx[i], __shfl_xor(rAmx[i], o));
      }
    if (m == 0) {
      const int r0 = rbv * 128 + w * 32 + q * 4;
#pragma unroll
      for (int mi = 0; mi < 2; ++mi)
#pragma unroll
        for (int r = 0; r < 4; ++r) {
          int row = r0 + mi * 16 + r;
          atomicMin(&mnK[row], fkey(rAmn[mi * 4 + r]));
          atomicMax(&mxK[row], fkey(rAmx[mi * 4 + r]));
        }
    }
  };

  stage(0, ct);   // prologue: first tile into buffer 0
  int p = 0;

#pragma unroll 1
  for (int f = t0; f < t1; ++f) {
    __syncthreads();   // buf[p] staged (compiler drains vmcnt pre-barrier)

    // next task coords (needed for prefetch target)
    int nct = ct + 1, nrb = rb;
    if (nct == nt) { ++nrb; nct = 2 * nrb; }
    if (f + 1 < t1) stage(p ^ 1, nct);   // async prefetch FIRST

    const int rt64 = 2 * rb + (w >> 1);
    if (rt64 <= ct) {
      any = true;
      floatx4 acc[2][4];
#pragma unroll
      for (int mi = 0; mi < 2; ++mi)
#pragma unroll
        for (int nj = 0; nj < 4; ++nj) acc[mi][nj] = (floatx4)0.0f;
#pragma unroll
      for (int ks = 0; ks < NKS; ++ks) {
        half8 b[4];
#pragma unroll
        for (int nj = 0; nj < 4; ++nj)
          b[nj] = *(const half8*)&Bs[p][((ks * 4 + nj) * 64 + l) * 8];
#pragma unroll
        for (int mi = 0; mi < 2; ++mi)
#pragma unroll
          for (int nj = 0; nj < 4; ++nj)
            acc[mi][nj] = __builtin_amdgcn_mfma_f32_16x16x32_f16(
                apan[ks][mi], b[nj], acc[mi][nj], 0, 0, 0);
      }
      // ---- epilogue: biased extremes; C/D col = nj*16+m, row = mi*16+q*4+r
      float cMn[4], cMx[4];
#pragma unroll
      for (int nj = 0; nj < 4; ++nj) {
        float a0 = fminf(fminf(acc[0][nj][0], acc[0][nj][1]),
                         fminf(acc[0][nj][2], acc[0][nj][3]));
        float a1 = fminf(fminf(acc[1][nj][0], acc[1][nj][1]),
                         fminf(acc[1][nj][2], acc[1][nj][3]));
        float b0 = fmaxf(fmaxf(acc[0][nj][0], acc[0][nj][1]),
                         fmaxf(acc[0][nj][2], acc[0][nj][3]));
        float b1 = fmaxf(fmaxf(acc[1][nj][0], acc[1][nj][1]),
                         fmaxf(acc[1][nj][2], acc[1][nj][3]));
        cMn[nj] = fminf(a0, a1);
        cMx[nj] = fmaxf(b0, b1);
#pragma unroll
        for (int mi = 0; mi < 2; ++mi)
#pragma unroll
          for (int r = 0; r < 4; ++r) {
            rAmn[mi * 4 + r] = fminf(rAmn[mi * 4 + r], acc[mi][nj][r]);
            rAmx[mi * 4 + r] = fmaxf(rAmx[mi * 4 + r], acc[mi][nj][r]);
          }
      }
#pragma unroll
      for (int nj = 0; nj < 4; ++nj) {
        cMn[nj] = fminf(cMn[nj], __shfl_xor(cMn[nj], 16));
        cMn[nj] = fminf(cMn[nj], __shfl_xor(cMn[nj], 32));
        cMx[nj] = fmaxf(cMx[nj], __shfl_xor(cMx[nj], 16));
        cMx[nj] = fmaxf(cMx[nj], __shfl_xor(cMx[nj], 32));
      }
      if (q == 0) {
#pragma unroll
        for (int nj = 0; nj < 4; ++nj) {
          int col = ct * 64 + nj * 16 + m;
          atomicMin(&mnK[col], fkey(cMn[nj]));
          atomicMax(&mxK[col], fkey(cMx[nj]));
        }
      }
    }
    // advance; flush on EVERY rb-crossing (R15 fix)
    if (nrb != rb) {
      flushRows(rb);
#pragma unroll
      for (int i = 0; i < 8; ++i) { rAmn[i] = 100.0f; rAmx[i] = -100.0f; }
      any = false;
      if (f + 1 < t1) loadA(nrb);
    }
    rb = nrb; ct = nct; p ^= 1;
  }
  flushRows(rb);   // no-op (any==false) if last task closed an rb
}

// K3: one thread per row. biasedMin = f(mnK)-10 (= minSame-8 iff < -4);
// biasedMax = f(mxK)-10 (= maxDiff iff > -4).
__global__ __launch_bounds__(256) void reduce_kernel(
    const unsigned* __restrict__ mnK, const unsigned* __restrict__ mxK,
    float* __restrict__ sumAcc, int* __restrict__ cntAcc,
    int* __restrict__ doneCnt, float* __restrict__ out, int B) {
  int gid = blockIdx.x * 256 + threadIdx.x;
  float loss = 0.0f;
  int cc = 0;
  if (gid < B) {
    float bmn = __builtin_bit_cast(float, mnK[gid]) - 10.0f;
    float bmx = __builtin_bit_cast(float, mxK[gid]) - 10.0f;
    if (bmn < -4.0f && bmx > -4.0f) {   // has same && has diff
      loss = fmaxf(bmx - (bmn + 8.0f) + MARGIN, 0.0f);
      cc = 1;
    }
  }
#pragma unroll
  for (int o = 1; o < 64; o <<= 1) {
    loss += __shfl_xor(loss, o);
    cc   += __shfl_xor(cc, o);
  }
  __shared__ float ls[4];
  __shared__ int   cs[4];
  if ((threadIdx.x & 63) == 0) {
    ls[threadIdx.x >> 6] = loss;
    cs[threadIdx.x >> 6] = cc;
  }
  __syncthreads();
  if (threadIdx.x == 0) {
    atomicAdd(sumAcc, ls[0] + ls[1] + ls[2] + ls[3]);
    atomicAdd(cntAcc, cs[0] + cs[1] + cs[2] + cs[3]);
    __threadfence();
    int old = atomicAdd(doneCnt, 1);
    if (old == (int)gridDim.x - 1) {
      float S = atomicAdd(sumAcc, 0.0f);   // coherent read
      int   C = atomicAdd(cntAcc, 0);
      out[0] = S / (float)(C > 0 ? C : 1);
    }
  }
}

extern "C" void kernel_launch(void* const* d_in, const int* in_sizes, int n_in,
                              void* d_out, int out_size, void* d_ws, size_t ws_size,
                              hipStream_t stream) {
  const float* E      = (const float*)d_in[0];
  const int*   labels = (const int*)d_in[1];
  float*       out    = (float*)d_out;
  const int B  = in_sizes[1];        // 8192
  const int nt = B / 64;             // 128 col tiles
  const int RB = B / 128;            // 64 row panels of 128 rows
  const int nTasks = RB * (nt - RB + 1);   // 64*65 = 4160

  // ws: EhB[nt*36KB] (4.72MB) | mnK[B] | mxK[B] | accums  (~4.79MB)
  unsigned short* EhB = (unsigned short*)d_ws;
  unsigned* mnK       = (unsigned*)(EhB + (size_t)nt * TILE_USH);
  unsigned* mxK       = mnK + B;
  float* sumAcc       = (float*)(mxK + B);
  int* cntAcc         = (int*)(sumAcc + 1);
  int* doneCnt        = cntAcc + 1;

  prep_kernel<<<dim3(256), 256, 0, stream>>>(E, labels, EhB, mnK, mxK,
                                             sumAcc, cntAcc, doneCnt, B);
  // grid 512 = exactly 2 blocks/CU (LDS 72KB/block caps residency at 2)
  gram_kernel<<<dim3(512), 256, 0, stream>>>(EhB, mnK, mxK, nt, nTasks);
  reduce_kernel<<<dim3((B + 255) / 256), 256, 0, stream>>>(
      mnK, mxK, sumAcc, cntAcc, doneCnt, out, B);
}